// Round 9
// baseline (261.561 us; speedup 1.0000x reference)
//
#include <hip/hip_runtime.h>
#include <math.h>

#define NB 2
#define NQ 8192
#define NL 8192
#define NC 128
#define NKN 8
#define NF 512
#define MQ (NB*NQ)   // 16384 rows total (both batches)

typedef __attribute__((ext_vector_type(8))) short bf16x8;
typedef __attribute__((ext_vector_type(4))) float f32x4;

__device__ __forceinline__ unsigned short f2bf_u(float f){
    unsigned u = __float_as_uint(f);
    return (unsigned short)((u + 0x7FFFu + ((u>>16)&1u)) >> 16);
}
__device__ __forceinline__ float bf2f(unsigned short s){
    return __uint_as_float(((unsigned)s) << 16);
}

// ===========================================================================
// Radius top-8 via uniform spatial grid, 16^3 cells per batch.
// ===========================================================================

__device__ __forceinline__ int cell_coord(float x) {
    int c = (int)(x * 16.0f);
    return min(15, max(0, c));
}

__global__ __launch_bounds__(256) void grid_count_kernel(
    const float* __restrict__ kxyz, const unsigned char* __restrict__ pad,
    int* __restrict__ cnt)
{
    int t = blockIdx.x*256 + threadIdx.x;
    if (pad[t]) return;
    int bat = t >> 13;
    float x = kxyz[t*3+0], y = kxyz[t*3+1], z = kxyz[t*3+2];
    int cell = (cell_coord(z)*16 + cell_coord(y))*16 + cell_coord(x);
    atomicAdd(&cnt[bat*4096 + cell], 1);
}

__global__ __launch_bounds__(1024) void grid_scan_kernel(
    const int* __restrict__ cnt, int* __restrict__ cs)
{
    __shared__ int wsum[17];
    int t = threadIdx.x;
    int v[8]; int s = 0;
    #pragma unroll
    for (int k = 0; k < 8; ++k) { v[k] = s; s += cnt[t*8 + k]; }
    int lane = t & 63, w = t >> 6;
    int inc = s;
    #pragma unroll
    for (int d = 1; d < 64; d <<= 1) {
        int o = __shfl_up(inc, d);
        if (lane >= d) inc += o;
    }
    if (lane == 63) wsum[w] = inc;
    __syncthreads();
    if (t == 0) {
        int a = 0;
        for (int i = 0; i < 16; ++i) { int x = wsum[i]; wsum[i] = a; a += x; }
        wsum[16] = a;
    }
    __syncthreads();
    int base = wsum[w] + (inc - s);
    #pragma unroll
    for (int k = 0; k < 8; ++k) cs[t*8 + k] = base + v[k];
    if (t == 1023) cs[8192] = wsum[16];
}

__global__ __launch_bounds__(256) void grid_scatter_kernel(
    const float* __restrict__ kxyz, const unsigned char* __restrict__ pad,
    const int* __restrict__ cs, int* __restrict__ fill, float4* __restrict__ ro)
{
    int t = blockIdx.x*256 + threadIdx.x;
    if (pad[t]) return;
    int bat = t >> 13, i = t & 8191;
    float x = kxyz[t*3+0], y = kxyz[t*3+1], z = kxyz[t*3+2];
    int cell = bat*4096 + (cell_coord(z)*16 + cell_coord(y))*16 + cell_coord(x);
    int pos = cs[cell] + atomicAdd(&fill[cell], 1);
    ro[pos] = make_float4(x, y, z, __int_as_float(i));
}

__device__ __forceinline__ void insert8(float cd, int id, float dk[8], int ik[8]) {
    if (cd < dk[7]) {
        dk[7] = cd; ik[7] = id;
        #pragma unroll
        for (int r = 6; r >= 0; --r) {
            bool sw = dk[r+1] < dk[r];
            float td = dk[r]; int ti = ik[r];
            dk[r]   = sw ? dk[r+1] : dk[r];
            ik[r]   = sw ? ik[r+1] : ik[r];
            dk[r+1] = sw ? td : dk[r+1];
            ik[r+1] = sw ? ti : ik[r+1];
        }
    }
}

template<int W>
__device__ __forceinline__ void scan_block(int l, int cx, int cy, int cz,
    float qx, float qy, float qz, const int* __restrict__ CS,
    const float4* __restrict__ RO, float dk[8], int ik[8])
{
    const int D = 2*W + 1;
    int xs = max(0, cx - W), xe = min(15, cx + W);
    int nx = xe - xs + 1;
    for (int r = l; r < D*D; r += 8) {
        int dz = r / D - W, dy = r % D - W;
        int zz = cz + dz, yy = cy + dy;
        if ((unsigned)zz > 15u || (unsigned)yy > 15u) continue;
        int c0 = (zz*16 + yy)*16 + xs;
        int s = CS[c0], e = CS[c0 + nx];
        for (int p = s; p < e; ++p) {
            float4 v = RO[p];
            float dx = qx - v.x, dyv = qy - v.y, dzv = qz - v.z;
            float cd = dx*dx + dyv*dyv + dzv*dzv;
            insert8(cd, __float_as_int(v.w), dk, ik);
        }
    }
}

__device__ __forceinline__ void merge8(float dk[8], int ik[8]) {
    #pragma unroll
    for (int m = 1; m <= 4; m <<= 1) {
        float od[8]; int oi[8];
        #pragma unroll
        for (int r = 0; r < 8; ++r) {
            od[r] = __shfl_xor(dk[r], m);
            oi[r] = __shfl_xor(ik[r], m);
        }
        float nd[8]; int ni[8];
        #pragma unroll
        for (int r = 0; r < 8; ++r) {
            bool take = od[7-r] < dk[r];
            nd[r] = take ? od[7-r] : dk[r];
            ni[r] = take ? oi[7-r] : ik[r];
        }
        #pragma unroll
        for (int st = 4; st >= 1; st >>= 1) {
            #pragma unroll
            for (int r = 0; r < 8; ++r) {
                if ((r & st) == 0 && (r | st) < 8) {
                    int b = r | st;
                    bool sw = nd[b] < nd[r];
                    float td = nd[r]; int ti = ni[r];
                    nd[r] = sw ? nd[b] : nd[r];
                    ni[r] = sw ? ni[b] : ni[r];
                    nd[b] = sw ? td : nd[b];
                    ni[b] = sw ? ti : ni[b];
                }
            }
        }
        #pragma unroll
        for (int r = 0; r < 8; ++r) { dk[r] = nd[r]; ik[r] = ni[r]; }
    }
}

__global__ __launch_bounds__(256) void radius_grid_query_kernel(
    const float* __restrict__ qxyz, const int* __restrict__ cellstart,
    const float4* __restrict__ reorder, int* __restrict__ idxout)
{
    const int tid  = threadIdx.x;
    const int l    = tid & 7;
    const int qloc = tid >> 3;
    const int gq   = blockIdx.x*32 + qloc;
    const int bat  = gq >> 13;
    const float qx = qxyz[gq*3+0], qy = qxyz[gq*3+1], qz = qxyz[gq*3+2];
    const int cx = cell_coord(qx), cy = cell_coord(qy), cz = cell_coord(qz);
    const int* CS = cellstart + bat*4096;
    const float R2  = (float)(0.4*0.4);
    const float R2P = __uint_as_float(__float_as_uint(R2) + 1u);

    float dk[8]; int ik[8];
    #pragma unroll
    for (int r = 0; r < 8; ++r) { dk[r] = R2P; ik[r] = -1; }

    scan_block<2>(l, cx, cy, cz, qx, qy, qz, CS, reorder, dk, ik);
    merge8(dk, ik);
    bool done = dk[7] <= 0.015625f;

    if (!done) {
        #pragma unroll
        for (int r = 0; r < 8; ++r) { dk[r] = R2P; ik[r] = -1; }
        scan_block<4>(l, cx, cy, cz, qx, qy, qz, CS, reorder, dk, ik);
        merge8(dk, ik);
        done = dk[7] <= 0.0625f;
    }
    if (!done) {
        #pragma unroll
        for (int r = 0; r < 8; ++r) { dk[r] = R2P; ik[r] = -1; }
        scan_block<16>(l, cx, cy, cz, qx, qy, qz, CS, reorder, dk, ik);
        merge8(dk, ik);
    }

    if (l == 0) {
        int o[8];
        #pragma unroll
        for (int r = 0; r < 8; ++r) o[r] = (dk[r] <= R2) ? ik[r] : -1;
        int4 a = {o[0], o[1], o[2], o[3]};
        int4 b = {o[4], o[5], o[6], o[7]};
        *(int4*)&idxout[(size_t)gq*8 + 0] = a;
        *(int4*)&idxout[(size_t)gq*8 + 4] = b;
    }
}

// ===========================================================================
// Unified weight prep + grid zero. Images: [chunk kk][col n][k&31] bf16,
// chunk stride Nd*32 ushorts, row stride 32 ushorts (64B).
// ushort offsets in imgb: wimg1 0, wimg2 16384, wvs 32768 (Nd=256),
// wd 65536, wf1 81920 (Nd=512), wf2 147456.
// Grid: 896 x 256; threads >= 212992 zero cellcnt+cellfill (16384 ints).
// ===========================================================================
__global__ __launch_bounds__(256) void prep_all_kernel(
    const float* __restrict__ posw2, const float* __restrict__ attnw,
    const float* __restrict__ lin_w, const float* __restrict__ lin_src_w,
    const float* __restrict__ lin_dst_w,
    const float* __restrict__ ffn_w1, const float* __restrict__ ffn_w2,
    unsigned short* __restrict__ imgb, int* __restrict__ zero_p)
{
    int t = blockIdx.x*256 + threadIdx.x;
    if (t < 16384) {
        int k = t >> 7, n = t & 127;
        imgb[(k >> 5)*4096 + n*32 + (k & 31)] = f2bf_u(posw2[t]);
    } else if (t < 32768) {
        int u = t - 16384;
        int k = u >> 7, n = u & 127;
        imgb[16384 + (k >> 5)*4096 + n*32 + (k & 31)] = f2bf_u(attnw[u]);
    } else if (t < 65536) {
        int u = t - 32768;
        int k = u >> 8, n = u & 255;
        float v = (n < 128) ? lin_w[k*128 + n] : lin_src_w[k*128 + (n-128)];
        imgb[32768 + ((k >> 5)*256 + n)*32 + (k & 31)] = f2bf_u(v);
    } else if (t < 81920) {
        int u = t - 65536;
        int k = u >> 7, n = u & 127;
        imgb[65536 + ((k >> 5)*128 + n)*32 + (k & 31)] = f2bf_u(lin_dst_w[u]);
    } else if (t < 147456) {
        int u = t - 81920;
        int k = u >> 9, n = u & 511;
        imgb[81920 + ((k >> 5)*512 + n)*32 + (k & 31)] = f2bf_u(ffn_w1[u]);
    } else if (t < 212992) {
        int u = t - 147456;
        int k = u >> 7, n = u & 127;
        imgb[147456 + ((k >> 5)*128 + n)*32 + (k & 31)] = f2bf_u(ffn_w2[u]);
    } else {
        zero_p[t - 212992] = 0;
    }
}

// ===========================================================================
// lin3: one launch for v|s (kv_feat @ [lin_w|lin_src_w], bf16 out, y=0,1)
// and adst (q_feat @ lin_dst_w, fp32 out, y=2). 64 rows x 128 cols / block.
// ===========================================================================
__global__ __launch_bounds__(256) void lin3_kernel(
    const float* __restrict__ kv_feat, const float* __restrict__ q_feat,
    const unsigned short* __restrict__ wvs, const unsigned short* __restrict__ wd,
    unsigned short* __restrict__ vs, float* __restrict__ adst)
{
    __shared__ unsigned short sA[64*32];
    __shared__ unsigned short sB[128*32];
    const int tid = threadIdx.x;
    const int w = tid >> 6, lane = tid & 63, l15 = lane & 15, quad = lane >> 4;
    const int row0 = blockIdx.x*64;
    const int y = blockIdx.y;
    const float* A = (y == 2) ? q_feat : kv_feat;
    const unsigned short* Bimg = (y == 2) ? wd : wvs;
    const int BNd = (y == 2) ? 128 : 256;
    const int col0 = (y == 2) ? 0 : y*128;

    f32x4 acc[8];
    #pragma unroll
    for (int t=0;t<8;t++){ acc[t][0]=0.f; acc[t][1]=0.f; acc[t][2]=0.f; acc[t][3]=0.f; }

    for (int kc = 0; kc < 4; ++kc) {
        __syncthreads();
        #pragma unroll
        for (int it = 0; it < 2; ++it) {
            int ix = it*256 + tid;
            int r = ix >> 3, kq = ix & 7;
            float4 a4 = *(const float4*)&A[(size_t)(row0+r)*NC + kc*32 + kq*4];
            ushort4 pk = { f2bf_u(a4.x), f2bf_u(a4.y), f2bf_u(a4.z), f2bf_u(a4.w) };
            *(ushort4*)&sA[r*32 + kq*4] = pk;
        }
        const int4* bsrc = (const int4*)(Bimg + ((size_t)kc*BNd + col0)*32);
        #pragma unroll
        for (int it = 0; it < 2; ++it) {
            int o = it*256 + tid;
            ((int4*)sB)[o] = bsrc[o];
        }
        __syncthreads();
        bf16x8 af = *(const bf16x8*)&sA[(w*16 + l15)*32 + quad*8];
        #pragma unroll
        for (int t = 0; t < 8; ++t) {
            bf16x8 bf = *(const bf16x8*)&sB[(16*t + l15)*32 + quad*8];
            acc[t] = __builtin_amdgcn_mfma_f32_16x16x32_bf16(af, bf, acc[t], 0, 0, 0);
        }
    }

    const int rowb = row0 + w*16 + quad*4;
    #pragma unroll
    for (int t = 0; t < 8; ++t) {
        int col = col0 + 16*t + l15;
        #pragma unroll
        for (int r = 0; r < 4; ++r) {
            if (y == 2) adst[(size_t)(rowb+r)*NC + col] = acc[t][r];
            else        vs[(size_t)(rowb+r)*256 + col] = f2bf_u(acc[t][r]);
        }
    }
}

// ===========================================================================
// Fused FFN: out = LN2(in1 + gelu(in1@wf1+b1)@wf2+b2).
// 128 thr = 2 waves; 32 rows/block (512 blocks). H never leaves the CU:
// per 128-col chunk, FFN1 MFMA -> gelu -> per-wave LDS tile (C->A transform)
// -> FFN2 MFMA accumulate. Weights read as coalesced 1KB/wave global frags
// from the prepped images (L2-hot).
// ===========================================================================
__device__ inline float gelu_exact(float x) {
    return 0.5f*x*(1.0f + erff(x*0.7071067811865476f));
}

__global__ __launch_bounds__(128) void ffn_fused_kernel(
    const float* __restrict__ in1,
    const unsigned short* __restrict__ wf1, const unsigned short* __restrict__ wf2,
    const float* __restrict__ b1v, const float* __restrict__ b2v,
    const float* __restrict__ g, const float* __restrict__ bb,
    float* __restrict__ out)
{
    __shared__ unsigned short sA[32*136];     // in1 bf16, A-frag layout (full 128 cols)
    __shared__ unsigned short sH[2*16*136];   // per-wave H tiles
    const int tid = threadIdx.x;
    const int w = tid >> 6, lane = tid & 63, l15 = lane & 15, quad = lane >> 4;
    const int row0 = blockIdx.x*32;

    // stage in1 rows: 32 rows x 128 cols = 1024 float4 -> 8 iters x 128 thr
    #pragma unroll
    for (int it = 0; it < 8; ++it) {
        int ix = it*128 + tid;              // 0..1023: r(32) x kq(32)
        int r = ix >> 5, kq = ix & 31;
        float4 a4 = *(const float4*)&in1[(size_t)(row0+r)*NC + kq*4];
        ushort4 pk = { f2bf_u(a4.x), f2bf_u(a4.y), f2bf_u(a4.z), f2bf_u(a4.w) };
        *(ushort4*)&sA[r*136 + kq*4] = pk;
    }
    __syncthreads();

    bf16x8 af[4];
    #pragma unroll
    for (int kk=0;kk<4;kk++)
        af[kk] = *(const bf16x8*)&sA[(w*16 + l15)*136 + kk*32 + quad*8];

    f32x4 acc2[8];
    #pragma unroll
    for (int t=0;t<8;t++){ acc2[t][0]=0.f; acc2[t][1]=0.f; acc2[t][2]=0.f; acc2[t][3]=0.f; }

    unsigned short* Hw = sH + w*16*136;

    #pragma unroll
    for (int c = 0; c < 4; ++c) {
        f32x4 acc1[8];
        #pragma unroll
        for (int t=0;t<8;t++){ acc1[t][0]=0.f; acc1[t][1]=0.f; acc1[t][2]=0.f; acc1[t][3]=0.f; }
        #pragma unroll
        for (int kk=0;kk<4;kk++){
            #pragma unroll
            for (int t=0;t<8;t++){
                int n = c*128 + 16*t + l15;
                bf16x8 bf = *(const bf16x8*)&wf1[((size_t)kk*512 + n)*32 + quad*8];
                acc1[t] = __builtin_amdgcn_mfma_f32_16x16x32_bf16(af[kk], bf, acc1[t], 0, 0, 0);
            }
        }
        #pragma unroll
        for (int t=0;t<8;t++){
            float bv = b1v[c*128 + 16*t + l15];
            #pragma unroll
            for (int r=0;r<4;r++){
                float x = gelu_exact(acc1[t][r] + bv);
                Hw[(quad*4+r)*136 + 16*t + l15] = f2bf_u(x);
            }
        }
        __syncthreads();   // H tile visible (also orders LDS within wave)
        #pragma unroll
        for (int kk=0;kk<4;kk++){
            bf16x8 a2 = *(const bf16x8*)&Hw[l15*136 + kk*32 + quad*8];
            #pragma unroll
            for (int t=0;t<8;t++){
                bf16x8 bf = *(const bf16x8*)&wf2[((size_t)((c*4+kk)*128) + 16*t + l15)*32 + quad*8];
                acc2[t] = __builtin_amdgcn_mfma_f32_16x16x32_bf16(a2, bf, acc2[t], 0, 0, 0);
            }
        }
        __syncthreads();   // reads done before next chunk overwrites H
    }

    const int rowb = row0 + w*16 + quad*4;
    #pragma unroll
    for (int r = 0; r < 4; ++r) {
        int row = rowb + r;
        float xv[8]; float S = 0.f;
        #pragma unroll
        for (int t = 0; t < 8; ++t) {
            int col = 16*t + l15;
            xv[t] = acc2[t][r] + b2v[col] + in1[(size_t)row*NC + col];
            S += xv[t];
        }
        #pragma unroll
        for (int m = 1; m <= 8; m <<= 1) S += __shfl_xor(S, m);
        float mean = S * (1.f/128.f);
        float V = 0.f;
        #pragma unroll
        for (int t = 0; t < 8; ++t) { float d = xv[t]-mean; V += d*d; }
        #pragma unroll
        for (int m = 1; m <= 8; m <<= 1) V += __shfl_xor(V, m);
        float rstd = rsqrtf(V*(1.f/128.f) + 1e-5f);
        #pragma unroll
        for (int t = 0; t < 8; ++t) {
            int col = 16*t + l15;
            out[(size_t)row*NC + col] = (xv[t]-mean)*rstd*g[col] + bb[col];
        }
    }
}

// ===========================================================================
// Fused per-edge attention (round-7 structure, unchanged).
// ===========================================================================
__global__ __launch_bounds__(256) void attn_mfma_kernel(
    const float* __restrict__ qxyz, const float* __restrict__ qfeat,
    const float* __restrict__ kxyz,
    const float* __restrict__ posw1, const float* __restrict__ posb1,
    const float* __restrict__ posb2, const float* __restrict__ attnb,
    const float* __restrict__ ln1g, const float* __restrict__ ln1b,
    const unsigned short* __restrict__ wimg1, const unsigned short* __restrict__ wimg2,
    const int* __restrict__ idx, const unsigned short* __restrict__ vs,
    const float* __restrict__ adst, float* __restrict__ out1)
{
    __shared__ unsigned short s_w[16384];
    __shared__ unsigned short s_V[4*16*136];
    __shared__ unsigned short s_T[4*16*136];
    __shared__ float s_w1[384];
    __shared__ float s_b1[128], s_b2[128], s_ab[128], s_g[128], s_bb[128];
    __shared__ int   s_j[64];

    const int tid  = threadIdx.x;
    const int w    = tid >> 6;
    const int lane = tid & 63;
    const int l15  = lane & 15;
    const int quad = lane >> 4;
    const int qbase = blockIdx.x*8 + w*2;
    const int bat  = (blockIdx.x*8) >> 13;

    if (tid < 128) {
        s_b1[tid] = posb1[tid]; s_b2[tid] = posb2[tid];
        s_ab[tid] = attnb[tid]; s_g[tid] = ln1g[tid]; s_bb[tid] = ln1b[tid];
    } else {
        int i = tid - 128;
        s_w1[i] = posw1[i]; s_w1[128+i] = posw1[128+i]; s_w1[256+i] = posw1[256+i];
    }
    if (tid < 64) s_j[tid] = idx[(size_t)blockIdx.x*64 + tid];
    #pragma unroll
    for (int r = 0; r < 8; ++r)
        ((int4*)s_w)[r*256 + tid] = ((const int4*)wimg1)[r*256 + tid];
    __syncthreads();

    #pragma unroll
    for (int i = 0; i < 4; ++i) {
        int ix = lane + i*64;
        int el = ix >> 4, c16 = ix & 15;
        int j = s_j[w*16 + el];
        int jc = j < 0 ? 0 : j;
        const int4* rp = (const int4*)(vs + ((size_t)(bat*NL + jc))*256);
        int dst = (w*16 + el)*136 + c16*8;
        *(int4*)&s_V[dst] = rp[c16];
        *(int4*)&s_T[dst] = rp[16 + c16];
    }

    bf16x8 h1f[4];
    {
        int e  = w*16 + l15;
        int qh = qbase + (l15 >> 3);
        int j  = s_j[e];
        int jc = j < 0 ? 0 : j;
        const float* kp = kxyz + ((size_t)(bat*NL + jc))*3;
        float rx = qxyz[qh*3+0]-kp[0], ry = qxyz[qh*3+1]-kp[1], rz = qxyz[qh*3+2]-kp[2];
        #pragma unroll
        for (int kk=0;kk<4;kk++){
            #pragma unroll
            for (int jj=0;jj<8;jj++){
                int c = kk*32 + quad*8 + jj;
                float h = s_b1[c] + rx*s_w1[c] + ry*s_w1[128+c] + rz*s_w1[256+c];
                h = fmaxf(h, 0.f);
                h1f[kk][jj] = (short)f2bf_u(h);
            }
        }
    }

    f32x4 acc[8];
    #pragma unroll
    for (int t=0;t<8;t++){ acc[t][0]=0.f; acc[t][1]=0.f; acc[t][2]=0.f; acc[t][3]=0.f; }
    #pragma unroll
    for (int kk=0;kk<4;kk++){
        #pragma unroll
        for (int t=0;t<8;t++){
            bf16x8 wf = *(const bf16x8*)&s_w[kk*4096 + (16*t + l15)*32 + quad*8];
            acc[t] = __builtin_amdgcn_mfma_f32_16x16x32_bf16(h1f[kk], wf, acc[t], 0, 0, 0);
        }
    }

    f32x4 dreg[8];
    #pragma unroll
    for (int t=0;t<8;t++){
        float b2v = s_b2[16*t + l15];
        #pragma unroll
        for (int r=0;r<4;r++) dreg[t][r] = fmaxf(acc[t][r] + b2v, 0.f);
    }

    int jr[4]; bool val[4];
    #pragma unroll
    for (int r=0;r<4;r++){
        int j = s_j[w*16 + quad*4 + r];
        val[r] = (j >= 0); jr[r] = j < 0 ? 0 : j;
    }
    const int qt = qbase + (quad >> 1);
    float ad[8];
    #pragma unroll
    for (int t=0;t<8;t++) ad[t] = adst[(size_t)qt*NC + 16*t + l15];

    __syncthreads();

    #pragma unroll
    for (int r = 0; r < 8; ++r)
        ((int4*)s_w)[r*256 + tid] = ((const int4*)wimg2)[r*256 + tid];

    {
        unsigned short* st = s_T + w*16*136;
        #pragma unroll
        for (int t=0;t<8;t++){
            #pragma unroll
            for (int r=0;r<4;r++){
                int o = (quad*4 + r)*136 + 16*t + l15;
                float sv = bf2f(st[o]);
                st[o] = f2bf_u(ad[t] - sv + dreg[t][r]);
            }
        }
    }
    __syncthreads();

    f32x4 acc2[8];
    #pragma unroll
    for (int t=0;t<8;t++){ acc2[t][0]=0.f; acc2[t][1]=0.f; acc2[t][2]=0.f; acc2[t][3]=0.f; }
    {
        const unsigned short* st = s_T + w*16*136;
        #pragma unroll
        for (int kk=0;kk<4;kk++){
            bf16x8 tf = *(const bf16x8*)&st[l15*136 + kk*32 + quad*8];
            #pragma unroll
            for (int t=0;t<8;t++){
                bf16x8 wf = *(const bf16x8*)&s_w[kk*4096 + (16*t + l15)*32 + quad*8];
                acc2[t] = __builtin_amdgcn_mfma_f32_16x16x32_bf16(tf, wf, acc2[t], 0, 0, 0);
            }
        }
    }

    float ex[8][4]; float dnm[8];
    #pragma unroll
    for (int t=0;t<8;t++){
        float ab = s_ab[16*t + l15];
        float s0 = val[0] ? fmaxf(acc2[t][0] + ab, 0.f) : -INFINITY;
        float s1 = val[1] ? fmaxf(acc2[t][1] + ab, 0.f) : -INFINITY;
        float s2 = val[2] ? fmaxf(acc2[t][2] + ab, 0.f) : -INFINITY;
        float s3 = val[3] ? fmaxf(acc2[t][3] + ab, 0.f) : -INFINITY;
        float mx = fmaxf(fmaxf(s0,s1), fmaxf(s2,s3));
        mx = fmaxf(mx, __shfl_xor(mx, 16));
        if (mx < -1e37f) mx = 0.f;
        ex[t][0] = __expf(s0 - mx);
        ex[t][1] = __expf(s1 - mx);
        ex[t][2] = __expf(s2 - mx);
        ex[t][3] = __expf(s3 - mx);
        float sm = ex[t][0]+ex[t][1]+ex[t][2]+ex[t][3];
        sm += __shfl_xor(sm, 16);
        dnm[t] = fmaxf(sm, 1e-12f);
    }

    float part[8];
    #pragma unroll
    for (int t=0;t<8;t++){
        float p = 0.f;
        #pragma unroll
        for (int r=0;r<4;r++){
            float vv = bf2f(s_V[(w*16 + quad*4 + r)*136 + 16*t + l15]);
            p += ex[t][r] * (vv + dreg[t][r]);
        }
        p += __shfl_xor(p, 16);
        part[t] = p / dnm[t];
    }

    float xln[8];
    float S = 0.f;
    #pragma unroll
    for (int t=0;t<8;t++){
        xln[t] = qfeat[(size_t)qt*NC + 16*t + l15] + part[t];
        S += xln[t];
    }
    #pragma unroll
    for (int m=1;m<=8;m<<=1) S += __shfl_xor(S, m);
    float mean = S * (1.f/128.f);
    float V = 0.f;
    #pragma unroll
    for (int t=0;t<8;t++){ float d = xln[t]-mean; V += d*d; }
    #pragma unroll
    for (int m=1;m<=8;m<<=1) V += __shfl_xor(V, m);
    float rstd = rsqrtf(V*(1.f/128.f) + 1e-5f);

    if ((quad & 1) == 0){
        #pragma unroll
        for (int t=0;t<8;t++){
            int c = 16*t + l15;
            out1[(size_t)qt*NC + c] = (xln[t]-mean)*rstd*s_g[c] + s_bb[c];
        }
    }
}

// ---------------------------------------------------------------------------
extern "C" void kernel_launch(void* const* d_in, const int* in_sizes, int n_in,
                              void* d_out, int out_size, void* d_ws, size_t ws_size,
                              hipStream_t stream)
{
    (void)in_sizes; (void)n_in; (void)out_size; (void)ws_size;
    const float* q_xyz   = (const float*)d_in[0];
    const float* q_feat  = (const float*)d_in[1];
    const float* kv_xyz  = (const float*)d_in[2];
    const float* kv_feat = (const float*)d_in[3];
    const unsigned char* kv_pad = (const unsigned char*)d_in[4];
    const float* pos_w1  = (const float*)d_in[5];
    const float* pos_b1  = (const float*)d_in[6];
    const float* pos_w2  = (const float*)d_in[7];
    const float* pos_b2  = (const float*)d_in[8];
    const float* attn_w  = (const float*)d_in[9];
    const float* attn_b  = (const float*)d_in[10];
    const float* lin_w   = (const float*)d_in[11];
    const float* lin_src_w = (const float*)d_in[12];
    const float* lin_dst_w = (const float*)d_in[13];
    const float* ln1_g   = (const float*)d_in[14];
    const float* ln1_b   = (const float*)d_in[15];
    const float* ffn_w1  = (const float*)d_in[16];
    const float* ffn_b1  = (const float*)d_in[17];
    const float* ffn_w2  = (const float*)d_in[18];
    const float* ffn_b2  = (const float*)d_in[19];
    const float* ln2_g   = (const float*)d_in[20];
    const float* ln2_b   = (const float*)d_in[21];

    float* ws    = (float*)d_ws;
    int*   idx   = (int*)d_ws;                                 // MQ*8 ints
    unsigned short* vs = (unsigned short*)(ws + 131072);       // [MQ,256] bf16 (v|s)
    float* adst  = ws + 131072 + 2*2097152;                    // [MQ,128] fp32
    float* out1  = adst + 2097152;                             // [MQ,128] fp32
    float* Hreg  = out1 + 2097152;                             // scratch region

    // grid-build scratch at Hreg start
    float4* reorder  = (float4*)Hreg;                // 256KB
    int* cellcnt   = (int*)(reorder + 16384);        // 8192
    int* cellfill  = cellcnt + 8192;                 // 8192
    int* cellstart = cellfill + 8192;                // 8193

    // weight images after grid scratch (offset 1MB into Hreg)
    unsigned short* imgb  = (unsigned short*)((char*)Hreg + (1u << 20));
    unsigned short* wimg1 = imgb;             // pos_w2    (16384)
    unsigned short* wimg2 = imgb + 16384;     // attn_w    (16384)
    unsigned short* wvs   = imgb + 32768;     // lin_w|lin_src_w (32768, Nd=256)
    unsigned short* wd    = imgb + 65536;     // lin_dst_w (16384)
    unsigned short* wf1   = imgb + 81920;     // ffn_w1    (65536, Nd=512)
    unsigned short* wf2   = imgb + 147456;    // ffn_w2    (65536)

    prep_all_kernel<<<dim3(896), dim3(256), 0, stream>>>(
        pos_w2, attn_w, lin_w, lin_src_w, lin_dst_w, ffn_w1, ffn_w2, imgb, cellcnt);

    grid_count_kernel<<<dim3(64), dim3(256), 0, stream>>>(kv_xyz, kv_pad, cellcnt);
    grid_scan_kernel<<<dim3(1), dim3(1024), 0, stream>>>(cellcnt, cellstart);
    grid_scatter_kernel<<<dim3(64), dim3(256), 0, stream>>>(kv_xyz, kv_pad, cellstart, cellfill, reorder);
    radius_grid_query_kernel<<<dim3(MQ/32), dim3(256), 0, stream>>>(q_xyz, cellstart, reorder, idx);

    lin3_kernel<<<dim3(MQ/64, 3), dim3(256), 0, stream>>>(kv_feat, q_feat, wvs, wd, vs, adst);

    attn_mfma_kernel<<<dim3(MQ/8), dim3(256), 0, stream>>>(
        q_xyz, q_feat, kv_xyz,
        pos_w1, pos_b1, pos_b2, attn_b, ln1_g, ln1_b,
        wimg1, wimg2, idx, vs, adst, out1);

    ffn_fused_kernel<<<dim3(MQ/32), dim3(128), 0, stream>>>(
        out1, wf1, wf2, ffn_b1, ffn_b2, ln2_g, ln2_b, (float*)d_out);
}

// Round 10
// 230.176 us; speedup vs baseline: 1.1364x; 1.1364x over previous
//
#include <hip/hip_runtime.h>
#include <math.h>

#define NB 2
#define NQ 8192
#define NL 8192
#define NC 128
#define NKN 8
#define NF 512
#define MQ (NB*NQ)   // 16384 rows total (both batches)

typedef __attribute__((ext_vector_type(8))) short bf16x8;
typedef __attribute__((ext_vector_type(4))) float f32x4;

__device__ __forceinline__ unsigned short f2bf_u(float f){
    unsigned u = __float_as_uint(f);
    return (unsigned short)((u + 0x7FFFu + ((u>>16)&1u)) >> 16);
}
__device__ __forceinline__ float bf2f(unsigned short s){
    return __uint_as_float(((unsigned)s) << 16);
}

// ===========================================================================
// Radius top-8 via uniform spatial grid, 16^3 cells per batch.
// ===========================================================================

__device__ __forceinline__ int cell_coord(float x) {
    int c = (int)(x * 16.0f);
    return min(15, max(0, c));
}

__global__ __launch_bounds__(256) void grid_count_kernel(
    const float* __restrict__ kxyz, const unsigned char* __restrict__ pad,
    int* __restrict__ cnt)
{
    int t = blockIdx.x*256 + threadIdx.x;
    if (pad[t]) return;
    int bat = t >> 13;
    float x = kxyz[t*3+0], y = kxyz[t*3+1], z = kxyz[t*3+2];
    int cell = (cell_coord(z)*16 + cell_coord(y))*16 + cell_coord(x);
    atomicAdd(&cnt[bat*4096 + cell], 1);
}

__global__ __launch_bounds__(1024) void grid_scan_kernel(
    const int* __restrict__ cnt, int* __restrict__ cs)
{
    __shared__ int wsum[17];
    int t = threadIdx.x;
    int v[8]; int s = 0;
    #pragma unroll
    for (int k = 0; k < 8; ++k) { v[k] = s; s += cnt[t*8 + k]; }
    int lane = t & 63, w = t >> 6;
    int inc = s;
    #pragma unroll
    for (int d = 1; d < 64; d <<= 1) {
        int o = __shfl_up(inc, d);
        if (lane >= d) inc += o;
    }
    if (lane == 63) wsum[w] = inc;
    __syncthreads();
    if (t == 0) {
        int a = 0;
        for (int i = 0; i < 16; ++i) { int x = wsum[i]; wsum[i] = a; a += x; }
        wsum[16] = a;
    }
    __syncthreads();
    int base = wsum[w] + (inc - s);
    #pragma unroll
    for (int k = 0; k < 8; ++k) cs[t*8 + k] = base + v[k];
    if (t == 1023) cs[8192] = wsum[16];
}

__global__ __launch_bounds__(256) void grid_scatter_kernel(
    const float* __restrict__ kxyz, const unsigned char* __restrict__ pad,
    const int* __restrict__ cs, int* __restrict__ fill, float4* __restrict__ ro)
{
    int t = blockIdx.x*256 + threadIdx.x;
    if (pad[t]) return;
    int bat = t >> 13, i = t & 8191;
    float x = kxyz[t*3+0], y = kxyz[t*3+1], z = kxyz[t*3+2];
    int cell = bat*4096 + (cell_coord(z)*16 + cell_coord(y))*16 + cell_coord(x);
    int pos = cs[cell] + atomicAdd(&fill[cell], 1);
    ro[pos] = make_float4(x, y, z, __int_as_float(i));
}

__device__ __forceinline__ void insert8(float cd, int id, float dk[8], int ik[8]) {
    if (cd < dk[7]) {
        dk[7] = cd; ik[7] = id;
        #pragma unroll
        for (int r = 6; r >= 0; --r) {
            bool sw = dk[r+1] < dk[r];
            float td = dk[r]; int ti = ik[r];
            dk[r]   = sw ? dk[r+1] : dk[r];
            ik[r]   = sw ? ik[r+1] : ik[r];
            dk[r+1] = sw ? td : dk[r+1];
            ik[r+1] = sw ? ti : ik[r+1];
        }
    }
}

template<int W>
__device__ __forceinline__ void scan_block(int l, int cx, int cy, int cz,
    float qx, float qy, float qz, const int* __restrict__ CS,
    const float4* __restrict__ RO, float dk[8], int ik[8])
{
    const int D = 2*W + 1;
    int xs = max(0, cx - W), xe = min(15, cx + W);
    int nx = xe - xs + 1;
    for (int r = l; r < D*D; r += 8) {
        int dz = r / D - W, dy = r % D - W;
        int zz = cz + dz, yy = cy + dy;
        if ((unsigned)zz > 15u || (unsigned)yy > 15u) continue;
        int c0 = (zz*16 + yy)*16 + xs;
        int s = CS[c0], e = CS[c0 + nx];
        for (int p = s; p < e; ++p) {
            float4 v = RO[p];
            float dx = qx - v.x, dyv = qy - v.y, dzv = qz - v.z;
            float cd = dx*dx + dyv*dyv + dzv*dzv;
            insert8(cd, __float_as_int(v.w), dk, ik);
        }
    }
}

__device__ __forceinline__ void merge8(float dk[8], int ik[8]) {
    #pragma unroll
    for (int m = 1; m <= 4; m <<= 1) {
        float od[8]; int oi[8];
        #pragma unroll
        for (int r = 0; r < 8; ++r) {
            od[r] = __shfl_xor(dk[r], m);
            oi[r] = __shfl_xor(ik[r], m);
        }
        float nd[8]; int ni[8];
        #pragma unroll
        for (int r = 0; r < 8; ++r) {
            bool take = od[7-r] < dk[r];
            nd[r] = take ? od[7-r] : dk[r];
            ni[r] = take ? oi[7-r] : ik[r];
        }
        #pragma unroll
        for (int st = 4; st >= 1; st >>= 1) {
            #pragma unroll
            for (int r = 0; r < 8; ++r) {
                if ((r & st) == 0 && (r | st) < 8) {
                    int b = r | st;
                    bool sw = nd[b] < nd[r];
                    float td = nd[r]; int ti = ni[r];
                    nd[r] = sw ? nd[b] : nd[r];
                    ni[r] = sw ? ni[b] : ni[r];
                    nd[b] = sw ? td : nd[b];
                    ni[b] = sw ? ti : ni[b];
                }
            }
        }
        #pragma unroll
        for (int r = 0; r < 8; ++r) { dk[r] = nd[r]; ik[r] = ni[r]; }
    }
}

__global__ __launch_bounds__(256) void radius_grid_query_kernel(
    const float* __restrict__ qxyz, const int* __restrict__ cellstart,
    const float4* __restrict__ reorder, int* __restrict__ idxout)
{
    const int tid  = threadIdx.x;
    const int l    = tid & 7;
    const int qloc = tid >> 3;
    const int gq   = blockIdx.x*32 + qloc;
    const int bat  = gq >> 13;
    const float qx = qxyz[gq*3+0], qy = qxyz[gq*3+1], qz = qxyz[gq*3+2];
    const int cx = cell_coord(qx), cy = cell_coord(qy), cz = cell_coord(qz);
    const int* CS = cellstart + bat*4096;
    const float R2  = (float)(0.4*0.4);
    const float R2P = __uint_as_float(__float_as_uint(R2) + 1u);

    float dk[8]; int ik[8];
    #pragma unroll
    for (int r = 0; r < 8; ++r) { dk[r] = R2P; ik[r] = -1; }

    scan_block<2>(l, cx, cy, cz, qx, qy, qz, CS, reorder, dk, ik);
    merge8(dk, ik);
    bool done = dk[7] <= 0.015625f;

    if (!done) {
        #pragma unroll
        for (int r = 0; r < 8; ++r) { dk[r] = R2P; ik[r] = -1; }
        scan_block<4>(l, cx, cy, cz, qx, qy, qz, CS, reorder, dk, ik);
        merge8(dk, ik);
        done = dk[7] <= 0.0625f;
    }
    if (!done) {
        #pragma unroll
        for (int r = 0; r < 8; ++r) { dk[r] = R2P; ik[r] = -1; }
        scan_block<16>(l, cx, cy, cz, qx, qy, qz, CS, reorder, dk, ik);
        merge8(dk, ik);
    }

    if (l == 0) {
        int o[8];
        #pragma unroll
        for (int r = 0; r < 8; ++r) o[r] = (dk[r] <= R2) ? ik[r] : -1;
        int4 a = {o[0], o[1], o[2], o[3]};
        int4 b = {o[4], o[5], o[6], o[7]};
        *(int4*)&idxout[(size_t)gq*8 + 0] = a;
        *(int4*)&idxout[(size_t)gq*8 + 4] = b;
    }
}

// ===========================================================================
// Unified weight prep + grid zero (unchanged from round 9).
// ===========================================================================
__global__ __launch_bounds__(256) void prep_all_kernel(
    const float* __restrict__ posw2, const float* __restrict__ attnw,
    const float* __restrict__ lin_w, const float* __restrict__ lin_src_w,
    const float* __restrict__ lin_dst_w,
    const float* __restrict__ ffn_w1, const float* __restrict__ ffn_w2,
    unsigned short* __restrict__ imgb, int* __restrict__ zero_p)
{
    int t = blockIdx.x*256 + threadIdx.x;
    if (t < 16384) {
        int k = t >> 7, n = t & 127;
        imgb[(k >> 5)*4096 + n*32 + (k & 31)] = f2bf_u(posw2[t]);
    } else if (t < 32768) {
        int u = t - 16384;
        int k = u >> 7, n = u & 127;
        imgb[16384 + (k >> 5)*4096 + n*32 + (k & 31)] = f2bf_u(attnw[u]);
    } else if (t < 65536) {
        int u = t - 32768;
        int k = u >> 8, n = u & 255;
        float v = (n < 128) ? lin_w[k*128 + n] : lin_src_w[k*128 + (n-128)];
        imgb[32768 + ((k >> 5)*256 + n)*32 + (k & 31)] = f2bf_u(v);
    } else if (t < 81920) {
        int u = t - 65536;
        int k = u >> 7, n = u & 127;
        imgb[65536 + ((k >> 5)*128 + n)*32 + (k & 31)] = f2bf_u(lin_dst_w[u]);
    } else if (t < 147456) {
        int u = t - 81920;
        int k = u >> 9, n = u & 511;
        imgb[81920 + ((k >> 5)*512 + n)*32 + (k & 31)] = f2bf_u(ffn_w1[u]);
    } else if (t < 212992) {
        int u = t - 147456;
        int k = u >> 7, n = u & 127;
        imgb[147456 + ((k >> 5)*128 + n)*32 + (k & 31)] = f2bf_u(ffn_w2[u]);
    } else {
        zero_p[t - 212992] = 0;
    }
}

// ===========================================================================
// lin3 (unchanged from round 9).
// ===========================================================================
__global__ __launch_bounds__(256) void lin3_kernel(
    const float* __restrict__ kv_feat, const float* __restrict__ q_feat,
    const unsigned short* __restrict__ wvs, const unsigned short* __restrict__ wd,
    unsigned short* __restrict__ vs, float* __restrict__ adst)
{
    __shared__ unsigned short sA[64*32];
    __shared__ unsigned short sB[128*32];
    const int tid = threadIdx.x;
    const int w = tid >> 6, lane = tid & 63, l15 = lane & 15, quad = lane >> 4;
    const int row0 = blockIdx.x*64;
    const int y = blockIdx.y;
    const float* A = (y == 2) ? q_feat : kv_feat;
    const unsigned short* Bimg = (y == 2) ? wd : wvs;
    const int BNd = (y == 2) ? 128 : 256;
    const int col0 = (y == 2) ? 0 : y*128;

    f32x4 acc[8];
    #pragma unroll
    for (int t=0;t<8;t++){ acc[t][0]=0.f; acc[t][1]=0.f; acc[t][2]=0.f; acc[t][3]=0.f; }

    for (int kc = 0; kc < 4; ++kc) {
        __syncthreads();
        #pragma unroll
        for (int it = 0; it < 2; ++it) {
            int ix = it*256 + tid;
            int r = ix >> 3, kq = ix & 7;
            float4 a4 = *(const float4*)&A[(size_t)(row0+r)*NC + kc*32 + kq*4];
            ushort4 pk = { f2bf_u(a4.x), f2bf_u(a4.y), f2bf_u(a4.z), f2bf_u(a4.w) };
            *(ushort4*)&sA[r*32 + kq*4] = pk;
        }
        const int4* bsrc = (const int4*)(Bimg + ((size_t)kc*BNd + col0)*32);
        #pragma unroll
        for (int it = 0; it < 2; ++it) {
            int o = it*256 + tid;
            ((int4*)sB)[o] = bsrc[o];
        }
        __syncthreads();
        bf16x8 af = *(const bf16x8*)&sA[(w*16 + l15)*32 + quad*8];
        #pragma unroll
        for (int t = 0; t < 8; ++t) {
            bf16x8 bf = *(const bf16x8*)&sB[(16*t + l15)*32 + quad*8];
            acc[t] = __builtin_amdgcn_mfma_f32_16x16x32_bf16(af, bf, acc[t], 0, 0, 0);
        }
    }

    const int rowb = row0 + w*16 + quad*4;
    #pragma unroll
    for (int t = 0; t < 8; ++t) {
        int col = col0 + 16*t + l15;
        #pragma unroll
        for (int r = 0; r < 4; ++r) {
            if (y == 2) adst[(size_t)(rowb+r)*NC + col] = acc[t][r];
            else        vs[(size_t)(rowb+r)*256 + col] = f2bf_u(acc[t][r]);
        }
    }
}

// ===========================================================================
// Fused FFN v2: out = LN2(in1 + gelu(in1@wf1+b1)@wf2+b2).
// 128 thr = 2 waves; 16 rows/block (1024 blocks -> 4 blocks/CU, 8 waves/CU).
// K-SPLIT across waves: wave w handles FFN1 c-chunks {2w, 2w+1} (N cols
// w*256..w*256+255) and the matching K-half of FFN2. Each wave owns a
// private H LDS tile (C->A transform). Wave 1 spills its partial acc2 to
// LDS; wave 0 reduces + bias + residual + LN2 + store.
// Weights read as coalesced 16B frags from L2-resident images (256KB total).
// ===========================================================================
__device__ inline float gelu_exact(float x) {
    return 0.5f*x*(1.0f + erff(x*0.7071067811865476f));
}

__global__ __launch_bounds__(128) void ffn_fused_kernel(
    const float* __restrict__ in1,
    const unsigned short* __restrict__ wf1, const unsigned short* __restrict__ wf2,
    const float* __restrict__ b1v, const float* __restrict__ b2v,
    const float* __restrict__ g, const float* __restrict__ bb,
    float* __restrict__ out)
{
    __shared__ unsigned short sA[16*136];     // in1 bf16, A-frag layout (4.4KB)
    __shared__ unsigned short sH[2*16*136];   // per-wave H tiles (8.7KB)
    __shared__ float sR[16*132];              // wave-1 partial acc2 (8.4KB)
    const int tid = threadIdx.x;
    const int w = tid >> 6, lane = tid & 63, l15 = lane & 15, quad = lane >> 4;
    const int row0 = blockIdx.x*16;

    // stage in1: 16 rows x 128 cols = 512 float4 -> 4 iters x 128 thr
    #pragma unroll
    for (int it = 0; it < 4; ++it) {
        int ix = it*128 + tid;              // 0..511: r(16) x kq(32)
        int r = ix >> 5, kq = ix & 31;
        float4 a4 = *(const float4*)&in1[(size_t)(row0+r)*NC + kq*4];
        ushort4 pk = { f2bf_u(a4.x), f2bf_u(a4.y), f2bf_u(a4.z), f2bf_u(a4.w) };
        *(ushort4*)&sA[r*136 + kq*4] = pk;
    }
    __syncthreads();

    bf16x8 af[4];
    #pragma unroll
    for (int kk=0;kk<4;kk++)
        af[kk] = *(const bf16x8*)&sA[l15*136 + kk*32 + quad*8];

    f32x4 acc2[8];
    #pragma unroll
    for (int t=0;t<8;t++){ acc2[t][0]=0.f; acc2[t][1]=0.f; acc2[t][2]=0.f; acc2[t][3]=0.f; }

    unsigned short* Hw = sH + w*16*136;

    #pragma unroll
    for (int ci = 0; ci < 2; ++ci) {
        const int c = w*2 + ci;             // this wave's FFN1 col-chunk
        f32x4 acc1[8];
        #pragma unroll
        for (int t=0;t<8;t++){ acc1[t][0]=0.f; acc1[t][1]=0.f; acc1[t][2]=0.f; acc1[t][3]=0.f; }
        #pragma unroll
        for (int kk=0;kk<4;kk++){
            #pragma unroll
            for (int t=0;t<8;t++){
                int n = c*128 + 16*t + l15;
                bf16x8 bf = *(const bf16x8*)&wf1[((size_t)kk*512 + n)*32 + quad*8];
                acc1[t] = __builtin_amdgcn_mfma_f32_16x16x32_bf16(af[kk], bf, acc1[t], 0, 0, 0);
            }
        }
        #pragma unroll
        for (int t=0;t<8;t++){
            float bv = b1v[c*128 + 16*t + l15];
            #pragma unroll
            for (int r=0;r<4;r++){
                float x = gelu_exact(acc1[t][r] + bv);
                Hw[(quad*4+r)*136 + 16*t + l15] = f2bf_u(x);
            }
        }
        __syncthreads();   // order H writes before cross-lane frag reads
        #pragma unroll
        for (int kk=0;kk<4;kk++){
            bf16x8 a2 = *(const bf16x8*)&Hw[l15*136 + kk*32 + quad*8];
            #pragma unroll
            for (int t=0;t<8;t++){
                bf16x8 bf = *(const bf16x8*)&wf2[((size_t)((c*4+kk)*128) + 16*t + l15)*32 + quad*8];
                acc2[t] = __builtin_amdgcn_mfma_f32_16x16x32_bf16(a2, bf, acc2[t], 0, 0, 0);
            }
        }
        __syncthreads();   // reads done before next chunk overwrites H
    }

    // K-split reduction: wave 1 spills, wave 0 reduces + epilogue
    if (w == 1) {
        #pragma unroll
        for (int t=0;t<8;t++)
            #pragma unroll
            for (int r=0;r<4;r++)
                sR[(quad*4+r)*132 + 16*t + l15] = acc2[t][r];
    }
    __syncthreads();
    if (w == 0) {
        #pragma unroll
        for (int r = 0; r < 4; ++r) {
            int row = row0 + quad*4 + r;
            float xv[8]; float S = 0.f;
            #pragma unroll
            for (int t = 0; t < 8; ++t) {
                int col = 16*t + l15;
                float a = acc2[t][r] + sR[(quad*4+r)*132 + col];
                xv[t] = a + b2v[col] + in1[(size_t)row*NC + col];
                S += xv[t];
            }
            #pragma unroll
            for (int m = 1; m <= 8; m <<= 1) S += __shfl_xor(S, m);
            float mean = S * (1.f/128.f);
            float V = 0.f;
            #pragma unroll
            for (int t = 0; t < 8; ++t) { float d = xv[t]-mean; V += d*d; }
            #pragma unroll
            for (int m = 1; m <= 8; m <<= 1) V += __shfl_xor(V, m);
            float rstd = rsqrtf(V*(1.f/128.f) + 1e-5f);
            #pragma unroll
            for (int t = 0; t < 8; ++t) {
                int col = 16*t + l15;
                out[(size_t)row*NC + col] = (xv[t]-mean)*rstd*g[col] + bb[col];
            }
        }
    }
}

// ===========================================================================
// Fused per-edge attention (unchanged).
// ===========================================================================
__global__ __launch_bounds__(256) void attn_mfma_kernel(
    const float* __restrict__ qxyz, const float* __restrict__ qfeat,
    const float* __restrict__ kxyz,
    const float* __restrict__ posw1, const float* __restrict__ posb1,
    const float* __restrict__ posb2, const float* __restrict__ attnb,
    const float* __restrict__ ln1g, const float* __restrict__ ln1b,
    const unsigned short* __restrict__ wimg1, const unsigned short* __restrict__ wimg2,
    const int* __restrict__ idx, const unsigned short* __restrict__ vs,
    const float* __restrict__ adst, float* __restrict__ out1)
{
    __shared__ unsigned short s_w[16384];
    __shared__ unsigned short s_V[4*16*136];
    __shared__ unsigned short s_T[4*16*136];
    __shared__ float s_w1[384];
    __shared__ float s_b1[128], s_b2[128], s_ab[128], s_g[128], s_bb[128];
    __shared__ int   s_j[64];

    const int tid  = threadIdx.x;
    const int w    = tid >> 6;
    const int lane = tid & 63;
    const int l15  = lane & 15;
    const int quad = lane >> 4;
    const int qbase = blockIdx.x*8 + w*2;
    const int bat  = (blockIdx.x*8) >> 13;

    if (tid < 128) {
        s_b1[tid] = posb1[tid]; s_b2[tid] = posb2[tid];
        s_ab[tid] = attnb[tid]; s_g[tid] = ln1g[tid]; s_bb[tid] = ln1b[tid];
    } else {
        int i = tid - 128;
        s_w1[i] = posw1[i]; s_w1[128+i] = posw1[128+i]; s_w1[256+i] = posw1[256+i];
    }
    if (tid < 64) s_j[tid] = idx[(size_t)blockIdx.x*64 + tid];
    #pragma unroll
    for (int r = 0; r < 8; ++r)
        ((int4*)s_w)[r*256 + tid] = ((const int4*)wimg1)[r*256 + tid];
    __syncthreads();

    #pragma unroll
    for (int i = 0; i < 4; ++i) {
        int ix = lane + i*64;
        int el = ix >> 4, c16 = ix & 15;
        int j = s_j[w*16 + el];
        int jc = j < 0 ? 0 : j;
        const int4* rp = (const int4*)(vs + ((size_t)(bat*NL + jc))*256);
        int dst = (w*16 + el)*136 + c16*8;
        *(int4*)&s_V[dst] = rp[c16];
        *(int4*)&s_T[dst] = rp[16 + c16];
    }

    bf16x8 h1f[4];
    {
        int e  = w*16 + l15;
        int qh = qbase + (l15 >> 3);
        int j  = s_j[e];
        int jc = j < 0 ? 0 : j;
        const float* kp = kxyz + ((size_t)(bat*NL + jc))*3;
        float rx = qxyz[qh*3+0]-kp[0], ry = qxyz[qh*3+1]-kp[1], rz = qxyz[qh*3+2]-kp[2];
        #pragma unroll
        for (int kk=0;kk<4;kk++){
            #pragma unroll
            for (int jj=0;jj<8;jj++){
                int c = kk*32 + quad*8 + jj;
                float h = s_b1[c] + rx*s_w1[c] + ry*s_w1[128+c] + rz*s_w1[256+c];
                h = fmaxf(h, 0.f);
                h1f[kk][jj] = (short)f2bf_u(h);
            }
        }
    }

    f32x4 acc[8];
    #pragma unroll
    for (int t=0;t<8;t++){ acc[t][0]=0.f; acc[t][1]=0.f; acc[t][2]=0.f; acc[t][3]=0.f; }
    #pragma unroll
    for (int kk=0;kk<4;kk++){
        #pragma unroll
        for (int t=0;t<8;t++){
            bf16x8 wf = *(const bf16x8*)&s_w[kk*4096 + (16*t + l15)*32 + quad*8];
            acc[t] = __builtin_amdgcn_mfma_f32_16x16x32_bf16(h1f[kk], wf, acc[t], 0, 0, 0);
        }
    }

    f32x4 dreg[8];
    #pragma unroll
    for (int t=0;t<8;t++){
        float b2v = s_b2[16*t + l15];
        #pragma unroll
        for (int r=0;r<4;r++) dreg[t][r] = fmaxf(acc[t][r] + b2v, 0.f);
    }

    int jr[4]; bool val[4];
    #pragma unroll
    for (int r=0;r<4;r++){
        int j = s_j[w*16 + quad*4 + r];
        val[r] = (j >= 0); jr[r] = j < 0 ? 0 : j;
    }
    const int qt = qbase + (quad >> 1);
    float ad[8];
    #pragma unroll
    for (int t=0;t<8;t++) ad[t] = adst[(size_t)qt*NC + 16*t + l15];

    __syncthreads();

    #pragma unroll
    for (int r = 0; r < 8; ++r)
        ((int4*)s_w)[r*256 + tid] = ((const int4*)wimg2)[r*256 + tid];

    {
        unsigned short* st = s_T + w*16*136;
        #pragma unroll
        for (int t=0;t<8;t++){
            #pragma unroll
            for (int r=0;r<4;r++){
                int o = (quad*4 + r)*136 + 16*t + l15;
                float sv = bf2f(st[o]);
                st[o] = f2bf_u(ad[t] - sv + dreg[t][r]);
            }
        }
    }
    __syncthreads();

    f32x4 acc2[8];
    #pragma unroll
    for (int t=0;t<8;t++){ acc2[t][0]=0.f; acc2[t][1]=0.f; acc2[t][2]=0.f; acc2[t][3]=0.f; }
    {
        const unsigned short* st = s_T + w*16*136;
        #pragma unroll
        for (int kk=0;kk<4;kk++){
            bf16x8 tf = *(const bf16x8*)&st[l15*136 + kk*32 + quad*8];
            #pragma unroll
            for (int t=0;t<8;t++){
                bf16x8 wf = *(const bf16x8*)&s_w[kk*4096 + (16*t + l15)*32 + quad*8];
                acc2[t] = __builtin_amdgcn_mfma_f32_16x16x32_bf16(tf, wf, acc2[t], 0, 0, 0);
            }
        }
    }

    float ex[8][4]; float dnm[8];
    #pragma unroll
    for (int t=0;t<8;t++){
        float ab = s_ab[16*t + l15];
        float s0 = val[0] ? fmaxf(acc2[t][0] + ab, 0.f) : -INFINITY;
        float s1 = val[1] ? fmaxf(acc2[t][1] + ab, 0.f) : -INFINITY;
        float s2 = val[2] ? fmaxf(acc2[t][2] + ab, 0.f) : -INFINITY;
        float s3 = val[3] ? fmaxf(acc2[t][3] + ab, 0.f) : -INFINITY;
        float mx = fmaxf(fmaxf(s0,s1), fmaxf(s2,s3));
        mx = fmaxf(mx, __shfl_xor(mx, 16));
        if (mx < -1e37f) mx = 0.f;
        ex[t][0] = __expf(s0 - mx);
        ex[t][1] = __expf(s1 - mx);
        ex[t][2] = __expf(s2 - mx);
        ex[t][3] = __expf(s3 - mx);
        float sm = ex[t][0]+ex[t][1]+ex[t][2]+ex[t][3];
        sm += __shfl_xor(sm, 16);
        dnm[t] = fmaxf(sm, 1e-12f);
    }

    float part[8];
    #pragma unroll
    for (int t=0;t<8;t++){
        float p = 0.f;
        #pragma unroll
        for (int r=0;r<4;r++){
            float vv = bf2f(s_V[(w*16 + quad*4 + r)*136 + 16*t + l15]);
            p += ex[t][r] * (vv + dreg[t][r]);
        }
        p += __shfl_xor(p, 16);
        part[t] = p / dnm[t];
    }

    float xln[8];
    float S = 0.f;
    #pragma unroll
    for (int t=0;t<8;t++){
        xln[t] = qfeat[(size_t)qt*NC + 16*t + l15] + part[t];
        S += xln[t];
    }
    #pragma unroll
    for (int m=1;m<=8;m<<=1) S += __shfl_xor(S, m);
    float mean = S * (1.f/128.f);
    float V = 0.f;
    #pragma unroll
    for (int t=0;t<8;t++){ float d = xln[t]-mean; V += d*d; }
    #pragma unroll
    for (int m=1;m<=8;m<<=1) V += __shfl_xor(V, m);
    float rstd = rsqrtf(V*(1.f/128.f) + 1e-5f);

    if ((quad & 1) == 0){
        #pragma unroll
        for (int t=0;t<8;t++){
            int c = 16*t + l15;
            out1[(size_t)qt*NC + c] = (xln[t]-mean)*rstd*s_g[c] + s_bb[c];
        }
    }
}

// ---------------------------------------------------------------------------
extern "C" void kernel_launch(void* const* d_in, const int* in_sizes, int n_in,
                              void* d_out, int out_size, void* d_ws, size_t ws_size,
                              hipStream_t stream)
{
    (void)in_sizes; (void)n_in; (void)out_size; (void)ws_size;
    const float* q_xyz   = (const float*)d_in[0];
    const float* q_feat  = (const float*)d_in[1];
    const float* kv_xyz  = (const float*)d_in[2];
    const float* kv_feat = (const float*)d_in[3];
    const unsigned char* kv_pad = (const unsigned char*)d_in[4];
    const float* pos_w1  = (const float*)d_in[5];
    const float* pos_b1  = (const float*)d_in[6];
    const float* pos_w2  = (const float*)d_in[7];
    const float* pos_b2  = (const float*)d_in[8];
    const float* attn_w  = (const float*)d_in[9];
    const float* attn_b  = (const float*)d_in[10];
    const float* lin_w   = (const float*)d_in[11];
    const float* lin_src_w = (const float*)d_in[12];
    const float* lin_dst_w = (const float*)d_in[13];
    const float* ln1_g   = (const float*)d_in[14];
    const float* ln1_b   = (const float*)d_in[15];
    const float* ffn_w1  = (const float*)d_in[16];
    const float* ffn_b1  = (const float*)d_in[17];
    const float* ffn_w2  = (const float*)d_in[18];
    const float* ffn_b2  = (const float*)d_in[19];
    const float* ln2_g   = (const float*)d_in[20];
    const float* ln2_b   = (const float*)d_in[21];

    float* ws    = (float*)d_ws;
    int*   idx   = (int*)d_ws;                                 // MQ*8 ints
    unsigned short* vs = (unsigned short*)(ws + 131072);       // [MQ,256] bf16 (v|s)
    float* adst  = ws + 131072 + 2*2097152;                    // [MQ,128] fp32
    float* out1  = adst + 2097152;                             // [MQ,128] fp32
    float* Hreg  = out1 + 2097152;                             // scratch region

    // grid-build scratch at Hreg start
    float4* reorder  = (float4*)Hreg;                // 256KB
    int* cellcnt   = (int*)(reorder + 16384);        // 8192
    int* cellfill  = cellcnt + 8192;                 // 8192
    int* cellstart = cellfill + 8192;                // 8193

    // weight images after grid scratch (offset 1MB into Hreg)
    unsigned short* imgb  = (unsigned short*)((char*)Hreg + (1u << 20));
    unsigned short* wimg1 = imgb;             // pos_w2    (16384)
    unsigned short* wimg2 = imgb + 16384;     // attn_w    (16384)
    unsigned short* wvs   = imgb + 32768;     // lin_w|lin_src_w (32768, Nd=256)
    unsigned short* wd    = imgb + 65536;     // lin_dst_w (16384)
    unsigned short* wf1   = imgb + 81920;     // ffn_w1    (65536, Nd=512)
    unsigned short* wf2   = imgb + 147456;    // ffn_w2    (65536)

    prep_all_kernel<<<dim3(896), dim3(256), 0, stream>>>(
        pos_w2, attn_w, lin_w, lin_src_w, lin_dst_w, ffn_w1, ffn_w2, imgb, cellcnt);

    grid_count_kernel<<<dim3(64), dim3(256), 0, stream>>>(kv_xyz, kv_pad, cellcnt);
    grid_scan_kernel<<<dim3(1), dim3(1024), 0, stream>>>(cellcnt, cellstart);
    grid_scatter_kernel<<<dim3(64), dim3(256), 0, stream>>>(kv_xyz, kv_pad, cellstart, cellfill, reorder);
    radius_grid_query_kernel<<<dim3(MQ/32), dim3(256), 0, stream>>>(q_xyz, cellstart, reorder, idx);

    lin3_kernel<<<dim3(MQ/64, 3), dim3(256), 0, stream>>>(kv_feat, q_feat, wvs, wd, vs, adst);

    attn_mfma_kernel<<<dim3(MQ/8), dim3(256), 0, stream>>>(
        q_xyz, q_feat, kv_xyz,
        pos_w1, pos_b1, pos_b2, attn_b, ln1_g, ln1_b,
        wimg1, wimg2, idx, vs, adst, out1);

    ffn_fused_kernel<<<dim3(MQ/16), dim3(128), 0, stream>>>(
        out1, wf1, wf2, ffn_b1, ffn_b2, ln2_g, ln2_b, (float*)d_out);
}